// Round 9
// baseline (340.000 us; speedup 1.0000x reference)
//
#include <hip/hip_runtime.h>

#define DIM 1024
#define BATCH 4096

typedef __attribute__((ext_vector_type(8))) short short8v;
typedef __attribute__((ext_vector_type(4))) short short4v;
typedef __attribute__((ext_vector_type(4))) float f32x4;

// ---------------------------------------------------------------------------
// DPP wave-wide reductions (VALU pipe; result wave-uniform via readlane 63).
__device__ __forceinline__ float dpp_reduce_bcast(float x) {
  int v = __builtin_bit_cast(int, x);
#define DPP_STEP(ctrl)                                                        \
  {                                                                           \
    int s = __builtin_amdgcn_update_dpp(0, v, ctrl, 0xf, 0xf, true);          \
    v = __builtin_bit_cast(                                                   \
        int, __builtin_bit_cast(float, v) + __builtin_bit_cast(float, s));    \
  }
  DPP_STEP(0x111) DPP_STEP(0x112) DPP_STEP(0x114) DPP_STEP(0x118)
  DPP_STEP(0x142) DPP_STEP(0x143)
#undef DPP_STEP
  return __builtin_bit_cast(float, __builtin_amdgcn_readlane(v, 63));
}

// 8 interleaved reduce chains (R=2 row blocking: 4 dots x 2 rows).
__device__ __forceinline__ void dpp_reduce8_bcast(float* d) {
  int v[8];
#pragma unroll
  for (int i = 0; i < 8; ++i) v[i] = __builtin_bit_cast(int, d[i]);
#define STEP8(ctrl)                                                           \
  {                                                                           \
    int s[8];                                                                 \
    _Pragma("unroll") for (int i = 0; i < 8; ++i)                             \
        s[i] = __builtin_amdgcn_update_dpp(0, v[i], ctrl, 0xf, 0xf, true);    \
    _Pragma("unroll") for (int i = 0; i < 8; ++i)                             \
        v[i] = __builtin_bit_cast(int, __builtin_bit_cast(float, v[i]) +      \
                                           __builtin_bit_cast(float, s[i]));  \
  }
  STEP8(0x111) STEP8(0x112) STEP8(0x114) STEP8(0x118) STEP8(0x142) STEP8(0x143)
#undef STEP8
#pragma unroll
  for (int i = 0; i < 8; ++i)
    d[i] = __builtin_bit_cast(float, __builtin_amdgcn_readlane(v[i], 63));
}

// bf16 split helpers (RNE).
__device__ __forceinline__ short f2bf(float f) {
  unsigned u = __builtin_bit_cast(unsigned, f);
  u += 0x7FFFu + ((u >> 16) & 1u);
  return (short)(u >> 16);
}
__device__ __forceinline__ float bf2f(short h) {
  unsigned u = ((unsigned)(unsigned short)h) << 16;
  return __builtin_bit_cast(float, u);
}

// ---------------------------------------------------------------------------
// 2/||row||^2 for all rows of U and V. One wave per row.
__global__ __launch_bounds__(256) void prep_k(const float* __restrict__ U,
                                              const float* __restrict__ V,
                                              float* __restrict__ tinu,
                                              float* __restrict__ tinv) {
  int gw = (blockIdx.x * 256 + threadIdx.x) >> 6;
  int lane = threadIdx.x & 63;
  if (gw >= 2048) return;
  const float* src = (gw < 1024) ? (U + (size_t)gw * DIM) : (V + (size_t)(gw - 1024) * DIM);
  float s = 0.f;
#pragma unroll
  for (int q = 0; q < 4; ++q) {
    float4 v = *reinterpret_cast<const float4*>(src + q * 256 + lane * 4);
    s += v.x * v.x + v.y * v.y + v.z * v.z + v.w * v.w;
  }
  float tot = dpp_reduce_bcast(s);
  if (lane == 0) {
    float val = 2.0f / tot;
    if (gw < 1024) tinu[gw] = val; else tinv[gw - 1024] = val;
  }
}

__global__ __launch_bounds__(256) void sig_k(const float* __restrict__ p, float* __restrict__ sg) {
  int i = blockIdx.x * 256 + threadIdx.x;
  if (i < DIM) {
    sg[i] = 0.1f + 0.9f / (1.0f + __expf(-p[i]));  // 0.9*sigmoid(p)+0.1
  }
}

// ---------------------------------------------------------------------------
// Pairwise dots c_ab = u_a . u_b per group of 4 consecutive reflectors in
// APPLICATION ORDER (U ascending, V descending). Layout: (01,02,03,12,13,23).
__global__ __launch_bounds__(256) void pairs_k(const float* __restrict__ U,
                                               const float* __restrict__ V,
                                               float* __restrict__ cU,
                                               float* __restrict__ cV) {
  int gw = (blockIdx.x * 256 + threadIdx.x) >> 6;
  int lane = threadIdx.x & 63;
  if (gw >= 512) return;
  int isV = gw >= 256;
  int g = isV ? gw - 256 : gw;
  const float* R = isV ? V : U;
  int r0 = isV ? (DIM - 1 - 4 * g) : 4 * g;
  int dir = isV ? -1 : 1;
  float u[4][16];
#pragma unroll
  for (int rr = 0; rr < 4; ++rr) {
    const float* src = R + (size_t)(r0 + dir * rr) * DIM;
#pragma unroll
    for (int q = 0; q < 4; ++q) {
      float4 v = *reinterpret_cast<const float4*>(src + q * 256 + lane * 4);
      u[rr][q * 4 + 0] = v.x; u[rr][q * 4 + 1] = v.y;
      u[rr][q * 4 + 2] = v.z; u[rr][q * 4 + 3] = v.w;
    }
  }
  const int pa[6] = {0, 0, 0, 1, 1, 2};
  const int pb[6] = {1, 2, 3, 2, 3, 3};
  float* dst = (isV ? cV : cU) + (size_t)g * 6;
#pragma unroll
  for (int k = 0; k < 6; ++k) {
    float s = 0.f;
#pragma unroll
    for (int i = 0; i < 16; ++i) s = fmaf(u[pa[k]][i], u[pb[k]][i], s);
    s = dpp_reduce_bcast(s);
    if (lane == 0) dst[k] = s;
  }
}

// ---------------------------------------------------------------------------
// chain helpers. Register layout: reg q*4+j <-> elem q*256 + lane*4 + j.
template <int CMIN, int DIR>
__device__ __forceinline__ void load4(float (&u)[4][16], const float* __restrict__ R,
                                      int o, int lane) {
  int r0 = (DIR > 0) ? o : (DIM - 1 - o);
#pragma unroll
  for (int rr = 0; rr < 4; ++rr) {
    const float* src = R + (size_t)(r0 + DIR * rr) * DIM;
#pragma unroll
    for (int q = 0; q < 4; ++q) {
      if (q >= CMIN) {
        float4 v = *reinterpret_cast<const float4*>(src + q * 256 + lane * 4);
        u[rr][q * 4 + 0] = v.x; u[rr][q * 4 + 1] = v.y;
        u[rr][q * 4 + 2] = v.z; u[rr][q * 4 + 3] = v.w;
      }
    }
  }
}

template <int CMIN>
__device__ __forceinline__ float dotrow(const float (&t)[16], const float (&u)[16]) {
  float a0 = 0.f, a1 = 0.f, a2 = 0.f, a3 = 0.f;
#pragma unroll
  for (int q = 0; q < 4; ++q) {
    if (q >= CMIN) {
      a0 = fmaf(t[q * 4 + 0], u[q * 4 + 0], a0);
      a1 = fmaf(t[q * 4 + 1], u[q * 4 + 1], a1);
      a2 = fmaf(t[q * 4 + 2], u[q * 4 + 2], a2);
      a3 = fmaf(t[q * 4 + 3], u[q * 4 + 3], a3);
    }
  }
  return (a0 + a1) + (a2 + a3);
}

template <int CMIN>
__device__ __forceinline__ void axpy4(float (&t)[16], const float (&u)[4][16],
                                      const float* al) {
#pragma unroll
  for (int q = 0; q < 4; ++q) {
    if (q >= CMIN) {
#pragma unroll
      for (int j = 0; j < 4; ++j) {
        int i = q * 4 + j;
        t[i] = fmaf(-al[3], u[3][i],
               fmaf(-al[2], u[2][i],
               fmaf(-al[1], u[1][i],
               fmaf(-al[0], u[0][i], t[i]))));
      }
    }
  }
}

// Apply one group of 4 reflectors (compact-WY) to TWO accumulator rows.
template <int CMIN, int DIR>
__device__ __forceinline__ void apply_group2(float (&t0)[16], float (&t1)[16],
                                             const float (&u)[4][16], int o,
                                             const float* __restrict__ taus,
                                             const float* __restrict__ cg) {
  int r0 = (DIR > 0) ? o : (DIM - 1 - o);
  const float* c = cg + (size_t)(o >> 2) * 6;
  float d[8];
#pragma unroll
  for (int rr = 0; rr < 4; ++rr) d[rr] = dotrow<CMIN>(t0, u[rr]);
#pragma unroll
  for (int rr = 0; rr < 4; ++rr) d[4 + rr] = dotrow<CMIN>(t1, u[rr]);
  dpp_reduce8_bcast(d);
  float tu0 = taus[r0], tu1 = taus[r0 + DIR];
  float tu2 = taus[r0 + 2 * DIR], tu3 = taus[r0 + 3 * DIR];
  float al[4], be[4];
  al[0] = tu0 * d[0];
  al[1] = tu1 * fmaf(-al[0], c[0], d[1]);
  al[2] = tu2 * fmaf(-al[1], c[3], fmaf(-al[0], c[1], d[2]));
  al[3] = tu3 * fmaf(-al[2], c[5], fmaf(-al[1], c[4], fmaf(-al[0], c[2], d[3])));
  be[0] = tu0 * d[4];
  be[1] = tu1 * fmaf(-be[0], c[0], d[5]);
  be[2] = tu2 * fmaf(-be[1], c[3], fmaf(-be[0], c[1], d[6]));
  be[3] = tu3 * fmaf(-be[2], c[5], fmaf(-be[1], c[4], fmaf(-be[0], c[2], d[7])));
  axpy4<CMIN>(t0, u, al);
  axpy4<CMIN>(t1, u, be);
}

template <int CMIN, int DIR>
__device__ __forceinline__ void run_phase2(float (&t0)[16], float (&t1)[16],
                                           const float* __restrict__ R,
                                           int o0, int o1,
                                           const float* __restrict__ taus,
                                           const float* __restrict__ cg,
                                           int lane) {
  float A[4][16], B[4][16];
  load4<CMIN, DIR>(A, R, o0, lane);
  for (int o = o0; o < o1; o += 8) {
    load4<CMIN, DIR>(B, R, o + 4, lane);
    apply_group2<CMIN, DIR>(t0, t1, A, o, taus, cg);
    if (o + 8 < o1) load4<CMIN, DIR>(A, R, o + 8, lane);
    apply_group2<CMIN, DIR>(t0, t1, B, o + 4, taus, cg);
  }
}

// ---------------------------------------------------------------------------
// Half-chain kernel. Q_U = A.B (A = H0..H511 full; B = [[I,0],[0,B']]),
// Q_V = P1.P2 (P1 = [[I,0],[0,P1']] = Hv1023..Hv512; P2 = Hv511..Hv0 full).
// 1536 blocks, R=2 rows/wave, chains of 512 reflections -> 1.5 waves/SIMD.
//   b in [0,512):    U-A rows 2b       -> A_U f32 full (chunks 0,1 sg-scaled)
//   b in [512,768):  U-B rows 512+2b'  -> B' scattered bf16 [n][k] (sg-scaled)
//   b in [768,1280): V-A (P2) rows 2b' -> rows<512: P2top f32; else P2bt bf16 [n][k]
//   b in [1280,1536):V-B (P1') rows 512+2b' -> P1' f32 compact [r-512][c-512]
__global__ __launch_bounds__(64) void qchain_k(const float* __restrict__ U,
                                               const float* __restrict__ V,
                                               const float* __restrict__ tinu,
                                               const float* __restrict__ tinv,
                                               const float* __restrict__ sg,
                                               const float* __restrict__ cU,
                                               const float* __restrict__ cV,
                                               float* __restrict__ AU,
                                               short* __restrict__ BUthi,
                                               short* __restrict__ BUtlo,
                                               float* __restrict__ P2top,
                                               short* __restrict__ P2bthi,
                                               short* __restrict__ P2btlo,
                                               float* __restrict__ P1p) {
  const int b = blockIdx.x;
  const int lane = threadIdx.x;
  int row0;
  if (b < 512) row0 = 2 * b;
  else if (b < 768) row0 = 512 + 2 * (b - 512);
  else if (b < 1280) row0 = 2 * (b - 768);
  else row0 = 512 + 2 * (b - 1280);

  float t0[16], t1[16];
#pragma unroll
  for (int q = 0; q < 4; ++q)
#pragma unroll
    for (int j = 0; j < 4; ++j) {
      int e = q * 256 + lane * 4 + j;
      t0[q * 4 + j] = (e == row0) ? 1.0f : 0.0f;
      t1[q * 4 + j] = (e == row0 + 1) ? 1.0f : 0.0f;
    }

  if (b < 512) {
    // U-A: refl 0..511
    run_phase2<0, 1>(t0, t1, U, 0, 256, tinu, cU, lane);
    run_phase2<1, 1>(t0, t1, U, 256, 512, tinu, cU, lane);
    // fold D1: scale cols <512 (chunks 0,1)
#pragma unroll
    for (int q = 0; q < 2; ++q) {
      float4 v = *reinterpret_cast<const float4*>(sg + q * 256 + lane * 4);
      t0[q * 4 + 0] *= v.x; t0[q * 4 + 1] *= v.y; t0[q * 4 + 2] *= v.z; t0[q * 4 + 3] *= v.w;
      t1[q * 4 + 0] *= v.x; t1[q * 4 + 1] *= v.y; t1[q * 4 + 2] *= v.z; t1[q * 4 + 3] *= v.w;
    }
#pragma unroll
    for (int q = 0; q < 4; ++q) {
      float4 v0, v1;
      v0.x = t0[q*4+0]; v0.y = t0[q*4+1]; v0.z = t0[q*4+2]; v0.w = t0[q*4+3];
      v1.x = t1[q*4+0]; v1.y = t1[q*4+1]; v1.z = t1[q*4+2]; v1.w = t1[q*4+3];
      *reinterpret_cast<float4*>(AU + (size_t)row0 * DIM + q * 256 + lane * 4) = v0;
      *reinterpret_cast<float4*>(AU + (size_t)(row0 + 1) * DIM + q * 256 + lane * 4) = v1;
    }
  } else if (b < 768) {
    // U-B: refl 512..1023, chunks 2,3 only
    run_phase2<2, 1>(t0, t1, U, 512, 768, tinu, cU, lane);
    run_phase2<3, 1>(t0, t1, U, 768, 1024, tinu, cU, lane);
    // fold D2: scale cols >=512 (chunks 2,3)
#pragma unroll
    for (int q = 2; q < 4; ++q) {
      float4 v = *reinterpret_cast<const float4*>(sg + q * 256 + lane * 4);
      t0[q * 4 + 0] *= v.x; t0[q * 4 + 1] *= v.y; t0[q * 4 + 2] *= v.z; t0[q * 4 + 3] *= v.w;
      t1[q * 4 + 0] *= v.x; t1[q * 4 + 1] *= v.y; t1[q * 4 + 2] *= v.z; t1[q * 4 + 3] *= v.w;
    }
    // scatter bf16 [n][k]: n = col-512, k = row-512, ldb 512
    int k0 = row0 - 512;
#pragma unroll
    for (int q = 2; q < 4; ++q)
#pragma unroll
      for (int j = 0; j < 4; ++j) {
        int n = (q - 2) * 256 + lane * 4 + j;
        float f0 = t0[q * 4 + j], f1 = t1[q * 4 + j];
        short h0 = f2bf(f0), h1 = f2bf(f1);
        BUthi[(size_t)n * 512 + k0] = h0;
        BUthi[(size_t)n * 512 + k0 + 1] = h1;
        BUtlo[(size_t)n * 512 + k0] = f2bf(f0 - bf2f(h0));
        BUtlo[(size_t)n * 512 + k0 + 1] = f2bf(f1 - bf2f(h1));
      }
  } else if (b < 1280) {
    // V-A (P2): refl order o 512..1023 (i = 511..0)
    run_phase2<1, -1>(t0, t1, V, 512, 768, tinv, cV, lane);
    run_phase2<0, -1>(t0, t1, V, 768, 1024, tinv, cV, lane);
    if (row0 < 512) {
#pragma unroll
      for (int q = 0; q < 4; ++q) {
        float4 v0, v1;
        v0.x = t0[q*4+0]; v0.y = t0[q*4+1]; v0.z = t0[q*4+2]; v0.w = t0[q*4+3];
        v1.x = t1[q*4+0]; v1.y = t1[q*4+1]; v1.z = t1[q*4+2]; v1.w = t1[q*4+3];
        *reinterpret_cast<float4*>(P2top + (size_t)row0 * DIM + q * 256 + lane * 4) = v0;
        *reinterpret_cast<float4*>(P2top + (size_t)(row0 + 1) * DIM + q * 256 + lane * 4) = v1;
      }
    } else {
      // scatter bf16 [n][k]: n = col (0..1023), k = row-512, ldb 512
      int k0 = row0 - 512;
#pragma unroll
      for (int q = 0; q < 4; ++q)
#pragma unroll
        for (int j = 0; j < 4; ++j) {
          int n = q * 256 + lane * 4 + j;
          float f0 = t0[q * 4 + j], f1 = t1[q * 4 + j];
          short h0 = f2bf(f0), h1 = f2bf(f1);
          P2bthi[(size_t)n * 512 + k0] = h0;
          P2bthi[(size_t)n * 512 + k0 + 1] = h1;
          P2btlo[(size_t)n * 512 + k0] = f2bf(f0 - bf2f(h0));
          P2btlo[(size_t)n * 512 + k0 + 1] = f2bf(f1 - bf2f(h1));
        }
    }
  } else {
    // V-B (P1'): refl order o 0..511 (i = 1023..512), chunks 2,3
    run_phase2<3, -1>(t0, t1, V, 0, 256, tinv, cV, lane);
    run_phase2<2, -1>(t0, t1, V, 256, 512, tinv, cV, lane);
    int r = row0 - 512;
#pragma unroll
    for (int q = 2; q < 4; ++q) {
      float4 v0, v1;
      v0.x = t0[q*4+0]; v0.y = t0[q*4+1]; v0.z = t0[q*4+2]; v0.w = t0[q*4+3];
      v1.x = t1[q*4+0]; v1.y = t1[q*4+1]; v1.z = t1[q*4+2]; v1.w = t1[q*4+3];
      int c = (q - 2) * 256 + lane * 4;
      *reinterpret_cast<float4*>(P1p + (size_t)r * 512 + c) = v0;
      *reinterpret_cast<float4*>(P1p + (size_t)(r + 1) * 512 + c) = v1;
    }
  }
}

// ---------------------------------------------------------------------------
// Recombine GEMMs (one launch, 64 blocks):
//   bid<32:  R_U[1024x512] = split(A_U[:,512:]) @ B'Ut   (K=512)
//   bid>=32: R_V[512x1024] = split(P1')         @ P2bt   (K=512)
// 128x128 tile, BK=32, f32 output.
__global__ __launch_bounds__(256) void recomb_k(const float* __restrict__ AU,
                                                const float* __restrict__ P1p,
                                                const short* __restrict__ BUthi,
                                                const short* __restrict__ BUtlo,
                                                const short* __restrict__ P2bthi,
                                                const short* __restrict__ P2btlo,
                                                float* __restrict__ RU,
                                                float* __restrict__ RV) {
  const int bid = blockIdx.x;
  const float* A; const short* Bh_p; const short* Bl_p; float* Out;
  int lda, ldo, bm, bn;
  if (bid < 32) {
    bm = bid >> 2; bn = bid & 3;
    A = AU + 512; lda = DIM; Bh_p = BUthi; Bl_p = BUtlo; Out = RU; ldo = 512;
  } else {
    int x = bid - 32; bm = x >> 3; bn = x & 7;
    A = P1p; lda = 512; Bh_p = P2bthi; Bl_p = P2btlo; Out = RV; ldo = DIM;
  }

  __shared__ short Ah[128][40], Al[128][40], Bh[128][40], Bl[128][40];
  const int tid = threadIdx.x;
  const int wid = tid >> 6;
  const int wr = wid >> 1, wc = wid & 1;
  const int lane = tid & 63;
  const int l15 = lane & 15;
  const int k8 = (lane >> 4) << 3;

  f32x4 acc[4][4] = {};

  for (int kb = 0; kb < 512; kb += 32) {
    __syncthreads();
#pragma unroll
    for (int ii = 0; ii < 4; ++ii) {
      int flat = tid + ii * 256;
      int r = flat >> 3, kq = (flat & 7) << 2;
      float4 v = *reinterpret_cast<const float4*>(
          A + (size_t)(bm * 128 + r) * lda + kb + kq);
      short4v h, l;
      float fv[4] = {v.x, v.y, v.z, v.w};
#pragma unroll
      for (int j = 0; j < 4; ++j) {
        short hh = f2bf(fv[j]);
        h[j] = hh;
        l[j] = f2bf(fv[j] - bf2f(hh));
      }
      *reinterpret_cast<short4v*>(&Ah[r][kq]) = h;
      *reinterpret_cast<short4v*>(&Al[r][kq]) = l;
    }
#pragma unroll
    for (int ii = 0; ii < 2; ++ii) {
      int flat = tid + ii * 256;
      int n = flat >> 2, kk8 = (flat & 3) << 3;
      size_t off = (size_t)(bn * 128 + n) * 512 + kb + kk8;
      *reinterpret_cast<short8v*>(&Bh[n][kk8]) =
          *reinterpret_cast<const short8v*>(Bh_p + off);
      *reinterpret_cast<short8v*>(&Bl[n][kk8]) =
          *reinterpret_cast<const short8v*>(Bl_p + off);
    }
    __syncthreads();

    short8v ah[4], al_[4], bh[4], bl_[4];
#pragma unroll
    for (int m = 0; m < 4; ++m) {
      int r = wr * 64 + m * 16 + l15;
      ah[m] = *reinterpret_cast<const short8v*>(&Ah[r][k8]);
      al_[m] = *reinterpret_cast<const short8v*>(&Al[r][k8]);
    }
#pragma unroll
    for (int n = 0; n < 4; ++n) {
      int r = wc * 64 + n * 16 + l15;
      bh[n] = *reinterpret_cast<const short8v*>(&Bh[r][k8]);
      bl_[n] = *reinterpret_cast<const short8v*>(&Bl[r][k8]);
    }
#pragma unroll
    for (int m = 0; m < 4; ++m)
#pragma unroll
      for (int n = 0; n < 4; ++n) {
        acc[m][n] = __builtin_amdgcn_mfma_f32_16x16x32_bf16(ah[m], bh[n], acc[m][n], 0, 0, 0);
        acc[m][n] = __builtin_amdgcn_mfma_f32_16x16x32_bf16(ah[m], bl_[n], acc[m][n], 0, 0, 0);
        acc[m][n] = __builtin_amdgcn_mfma_f32_16x16x32_bf16(al_[m], bh[n], acc[m][n], 0, 0, 0);
      }
  }

#pragma unroll
  for (int n = 0; n < 4; ++n) {
    int gcol = bn * 128 + wc * 64 + n * 16 + l15;
#pragma unroll
    for (int m = 0; m < 4; ++m) {
      int grow0 = bm * 128 + wr * 64 + m * 16 + ((lane >> 4) << 2);
#pragma unroll
      for (int j = 0; j < 4; ++j) {
        Out[(size_t)(grow0 + j) * ldo + gcol] = acc[m][n][j];
      }
    }
  }
}

// ---------------------------------------------------------------------------
// Transpose + bf16 hi/lo split of QV: rows k<512 from P2top, k>=512 from RV.
__global__ __launch_bounds__(256) void mtsplit_k(const float* __restrict__ P2top,
                                                 const float* __restrict__ RV,
                                                 short* __restrict__ Mthi,
                                                 short* __restrict__ Mtlo) {
  __shared__ float tile[64][68];
  const int tr = blockIdx.y;  // k-tile (0..15)
  const int tc = blockIdx.x;  // n-tile
  const int f = threadIdx.x;
  const float* src = (tr < 8) ? (P2top + (size_t)tr * 64 * DIM)
                              : (RV + (size_t)(tr - 8) * 64 * DIM);
#pragma unroll
  for (int ii = 0; ii < 4; ++ii) {
    int flat = f + ii * 256;
    int r = flat >> 4, c4 = (flat & 15) << 2;
    float4 v = *reinterpret_cast<const float4*>(src + (size_t)r * DIM + tc * 64 + c4);
    tile[r][c4 + 0] = v.x; tile[r][c4 + 1] = v.y; tile[r][c4 + 2] = v.z; tile[r][c4 + 3] = v.w;
  }
  __syncthreads();
#pragma unroll
  for (int ii = 0; ii < 2; ++ii) {
    int flat = f + ii * 256;
    int nn = flat >> 3, k8 = (flat & 7) << 3;
    short8v vh, vl;
#pragma unroll
    for (int j = 0; j < 8; ++j) {
      float fv = tile[k8 + j][nn];
      short hh = f2bf(fv);
      vh[j] = hh;
      vl[j] = f2bf(fv - bf2f(hh));
    }
    size_t off = (size_t)(tc * 64 + nn) * DIM + tr * 64 + k8;
    *reinterpret_cast<short8v*>(Mthi + off) = vh;
    *reinterpret_cast<short8v*>(Mtlo + off) = vl;
  }
}

// ---------------------------------------------------------------------------
// M^T = (QU' @ QV)^T via split-bf16 MFMA; A = QU' as two-piece view
// (k<512: A_U; k>=512: R_U). Writes Mthi/Mtlo [n][k] directly.
__global__ __launch_bounds__(256) void mgemm_mfma_k(const float* __restrict__ AU,
                                                    const float* __restrict__ RU,
                                                    const short* __restrict__ Bthi,
                                                    const short* __restrict__ Btlo,
                                                    short* __restrict__ Mthi,
                                                    short* __restrict__ Mtlo) {
  __shared__ short Ah[128][40], Al[128][40], Bh[128][40], Bl[128][40];
  const int tid = threadIdx.x;
  const int bn = blockIdx.x;
  const int bm = blockIdx.y;
  const int wid = tid >> 6;
  const int wr = wid >> 1, wc = wid & 1;
  const int lane = tid & 63;
  const int l15 = lane & 15;
  const int k8 = (lane >> 4) << 3;

  f32x4 acc[4][4] = {};

  for (int kb = 0; kb < DIM; kb += 32) {
    __syncthreads();
    const float* abase; int alda;
    if (kb < 512) { abase = AU + kb; alda = DIM; }
    else          { abase = RU + (kb - 512); alda = 512; }
#pragma unroll
    for (int ii = 0; ii < 4; ++ii) {
      int flat = tid + ii * 256;
      int r = flat >> 3, kq = (flat & 7) << 2;
      float4 v = *reinterpret_cast<const float4*>(
          abase + (size_t)(bm * 128 + r) * alda + kq);
      short4v h, l;
      float fv[4] = {v.x, v.y, v.z, v.w};
#pragma unroll
      for (int j = 0; j < 4; ++j) {
        short hh = f2bf(fv[j]);
        h[j] = hh;
        l[j] = f2bf(fv[j] - bf2f(hh));
      }
      *reinterpret_cast<short4v*>(&Ah[r][kq]) = h;
      *reinterpret_cast<short4v*>(&Al[r][kq]) = l;
    }
#pragma unroll
    for (int ii = 0; ii < 2; ++ii) {
      int flat = tid + ii * 256;
      int n = flat >> 2, kk8 = (flat & 3) << 3;
      size_t off = (size_t)(bn * 128 + n) * DIM + kb + kk8;
      *reinterpret_cast<short8v*>(&Bh[n][kk8]) =
          *reinterpret_cast<const short8v*>(Bthi + off);
      *reinterpret_cast<short8v*>(&Bl[n][kk8]) =
          *reinterpret_cast<const short8v*>(Btlo + off);
    }
    __syncthreads();

    short8v ah[4], al_[4], bh[4], bl_[4];
#pragma unroll
    for (int m = 0; m < 4; ++m) {
      int r = wr * 64 + m * 16 + l15;
      ah[m] = *reinterpret_cast<const short8v*>(&Ah[r][k8]);
      al_[m] = *reinterpret_cast<const short8v*>(&Al[r][k8]);
    }
#pragma unroll
    for (int n = 0; n < 4; ++n) {
      int r = wc * 64 + n * 16 + l15;
      bh[n] = *reinterpret_cast<const short8v*>(&Bh[r][k8]);
      bl_[n] = *reinterpret_cast<const short8v*>(&Bl[r][k8]);
    }
#pragma unroll
    for (int m = 0; m < 4; ++m)
#pragma unroll
      for (int n = 0; n < 4; ++n) {
        acc[m][n] = __builtin_amdgcn_mfma_f32_16x16x32_bf16(ah[m], bh[n], acc[m][n], 0, 0, 0);
        acc[m][n] = __builtin_amdgcn_mfma_f32_16x16x32_bf16(ah[m], bl_[n], acc[m][n], 0, 0, 0);
        acc[m][n] = __builtin_amdgcn_mfma_f32_16x16x32_bf16(al_[m], bh[n], acc[m][n], 0, 0, 0);
      }
  }

#pragma unroll
  for (int n = 0; n < 4; ++n) {
    int gcol = bn * 128 + wc * 64 + n * 16 + l15;  // n index of M
#pragma unroll
    for (int m = 0; m < 4; ++m) {
      int gk0 = bm * 128 + wr * 64 + m * 16 + ((lane >> 4) << 2);  // k index
      short4v h, l;
#pragma unroll
      for (int j = 0; j < 4; ++j) {
        float fv = acc[m][n][j];
        short hh = f2bf(fv);
        h[j] = hh;
        l[j] = f2bf(fv - bf2f(hh));
      }
      *reinterpret_cast<short4v*>(Mthi + (size_t)gcol * DIM + gk0) = h;
      *reinterpret_cast<short4v*>(Mtlo + (size_t)gcol * DIM + gk0) = l;
    }
  }
}

// ---------------------------------------------------------------------------
// out[4096,1024] = x @ M + bias via split-bf16 MFMA.
__global__ __launch_bounds__(256) void gemm_mfma_k(const float* __restrict__ x,
                                                   const short* __restrict__ Bthi,
                                                   const short* __restrict__ Btlo,
                                                   const float* __restrict__ bias,
                                                   float* __restrict__ out) {
  __shared__ short Ah[128][40], Al[128][40], Bh[128][40], Bl[128][40];
  const int tid = threadIdx.x;
  const int bn = blockIdx.x;
  const int bm = blockIdx.y;
  const int wid = tid >> 6;
  const int wr = wid >> 1, wc = wid & 1;
  const int lane = tid & 63;
  const int l15 = lane & 15;
  const int k8 = (lane >> 4) << 3;

  f32x4 acc[4][4] = {};

  for (int kb = 0; kb < DIM; kb += 32) {
    __syncthreads();
#pragma unroll
    for (int ii = 0; ii < 4; ++ii) {
      int flat = tid + ii * 256;
      int r = flat >> 3, kq = (flat & 7) << 2;
      float4 v = *reinterpret_cast<const float4*>(
          x + (size_t)(bm * 128 + r) * DIM + kb + kq);
      short4v h, l;
      float fv[4] = {v.x, v.y, v.z, v.w};
#pragma unroll
      for (int j = 0; j < 4; ++j) {
        short hh = f2bf(fv[j]);
        h[j] = hh;
        l[j] = f2bf(fv[j] - bf2f(hh));
      }
      *reinterpret_cast<short4v*>(&Ah[r][kq]) = h;
      *reinterpret_cast<short4v*>(&Al[r][kq]) = l;
    }
#pragma unroll
    for (int ii = 0; ii < 2; ++ii) {
      int flat = tid + ii * 256;
      int n = flat >> 2, kk8 = (flat & 3) << 3;
      size_t off = (size_t)(bn * 128 + n) * DIM + kb + kk8;
      *reinterpret_cast<short8v*>(&Bh[n][kk8]) =
          *reinterpret_cast<const short8v*>(Bthi + off);
      *reinterpret_cast<short8v*>(&Bl[n][kk8]) =
          *reinterpret_cast<const short8v*>(Btlo + off);
    }
    __syncthreads();

    short8v ah[4], al_[4], bh[4], bl_[4];
#pragma unroll
    for (int m = 0; m < 4; ++m) {
      int r = wr * 64 + m * 16 + l15;
      ah[m] = *reinterpret_cast<const short8v*>(&Ah[r][k8]);
      al_[m] = *reinterpret_cast<const short8v*>(&Al[r][k8]);
    }
#pragma unroll
    for (int n = 0; n < 4; ++n) {
      int r = wc * 64 + n * 16 + l15;
      bh[n] = *reinterpret_cast<const short8v*>(&Bh[r][k8]);
      bl_[n] = *reinterpret_cast<const short8v*>(&Bl[r][k8]);
    }
#pragma unroll
    for (int m = 0; m < 4; ++m)
#pragma unroll
      for (int n = 0; n < 4; ++n) {
        acc[m][n] = __builtin_amdgcn_mfma_f32_16x16x32_bf16(ah[m], bh[n], acc[m][n], 0, 0, 0);
        acc[m][n] = __builtin_amdgcn_mfma_f32_16x16x32_bf16(ah[m], bl_[n], acc[m][n], 0, 0, 0);
        acc[m][n] = __builtin_amdgcn_mfma_f32_16x16x32_bf16(al_[m], bh[n], acc[m][n], 0, 0, 0);
      }
  }

#pragma unroll
  for (int n = 0; n < 4; ++n) {
    int gcol = bn * 128 + wc * 64 + n * 16 + l15;
    float bv = bias[gcol];
#pragma unroll
    for (int m = 0; m < 4; ++m) {
      int grow0 = bm * 128 + wr * 64 + m * 16 + ((lane >> 4) << 2);
#pragma unroll
      for (int j = 0; j < 4; ++j) {
        out[(size_t)(grow0 + j) * DIM + gcol] = acc[m][n][j] + bv;
      }
    }
  }
}

// ---------------------------------------------------------------------------
extern "C" void kernel_launch(void* const* d_in, const int* in_sizes, int n_in,
                              void* d_out, int out_size, void* d_ws, size_t ws_size,
                              hipStream_t stream) {
  const float* x    = (const float*)d_in[0];
  const float* U    = (const float*)d_in[1];
  const float* V    = (const float*)d_in[2];
  const float* p    = (const float*)d_in[3];
  const float* bias = (const float*)d_in[4];
  float* out = (float*)d_out;

  float* ws = (float*)d_ws;
  // Layout (float offsets), peak ~3.68M floats = 14.7 MB:
  //  [0,1M)        A_U f32            (live through mgemm: cols<512)
  //  [1M,1.5M)     R_V f32 512x1024   (dead after mtsplit)
  //  [1.5M,2M)     P2top f32 512x1024 (dead after mtsplit)
  //    -> Mthi/Mtlo (1M shorts each) reuse [1M,2M) after mtsplit
  //  [2M,3M)       scratch: BUthi/lo (512^2 sh each), P1' f32 (0.25M),
  //                P2bthi/lo (1024x512 sh each)
  //    -> QVthi/lo (1M shorts each) reuse [2M,3M) after recomb
  //  [3M,3.5M)     R_U f32 1024x512   (live through mgemm)
  //  [3.5M+,..)    smalls
  float* AU     = ws;
  float* RV     = ws + 1048576;
  float* P2top  = ws + 1572864;
  short* Mthi   = (short*)(ws + 1048576);
  short* Mtlo   = (short*)(ws + 1572864);
  float* S      = ws + 2097152;
  short* BUthi  = (short*)S;                       // 262144 shorts
  short* BUtlo  = BUthi + 262144;
  float* P1p    = S + 262144;                      // 0.25M floats
  short* P2bthi = (short*)(S + 524288);            // 524288 shorts
  short* P2btlo = (short*)(S + 786432);
  short* QVthi  = (short*)S;                       // reuse after recomb
  short* QVtlo  = (short*)(ws + 2621440);
  float* RU     = ws + 3145728;
  float* tinu   = ws + 3670016;
  float* tinv   = tinu + DIM;
  float* sg     = tinv + DIM;
  float* cU     = sg + DIM;        // 256*6
  float* cV     = cU + 256 * 6;    // 256*6

  prep_k<<<512, 256, 0, stream>>>(U, V, tinu, tinv);
  sig_k<<<DIM / 256, 256, 0, stream>>>(p, sg);
  pairs_k<<<128, 256, 0, stream>>>(U, V, cU, cV);
  qchain_k<<<1536, 64, 0, stream>>>(U, V, tinu, tinv, sg, cU, cV,
                                    AU, BUthi, BUtlo, P2top, P2bthi, P2btlo, P1p);
  recomb_k<<<64, 256, 0, stream>>>(AU, P1p, BUthi, BUtlo, P2bthi, P2btlo, RU, RV);
  mtsplit_k<<<dim3(16, 16), 256, 0, stream>>>(P2top, RV, QVthi, QVtlo);
  mgemm_mfma_k<<<dim3(8, 8), 256, 0, stream>>>(AU, RU, QVthi, QVtlo, Mthi, Mtlo);
  gemm_mfma_k<<<dim3(8, 32), 256, 0, stream>>>(x, Mthi, Mtlo, bias, out);
}